// Round 1
// baseline (5492.286 us; speedup 1.0000x reference)
//
#include <hip/hip_runtime.h>

// Seq2SeqLSTMForecaster on MI355X — round 11.
// R10 theory: kX (fp32 VALU GEMM, 90 GFLOP vs 157 TF vector ceiling) is the
// only big component with a hardware bypass: the idle 2.5 PF bf16 MFMA pipe.
// This round, ONE change: kX -> MFMA bf16 split-2 (hi+lo, 3 products =
// ~fp32 accuracy, ~830 TF effective).
//  - kA: identical except h is stored as bf16 hi/lo split in [dt][m][k]
//        layout (same bytes; contiguous stores) instead of fp32 ys0T.
//  - kXm: 128x128x128 block, 4 waves, A-frags straight from global (layout
//        already fragment-native), B in LDS with G4 XOR swizzle, 2 blk/CU.
//  - kPrep: + one block splitting eWih1 [512][128] ([n][k]!) into bf16 hi/lo.
//  - kB2/kD: byte-identical to round 10.

#define B_    1024
#define T_    672
#define H_    128
#define G_    512      // 4*H
#define TGT_  96
#define NBLK_ 256

typedef __attribute__((ext_vector_type(8))) short  short8;
typedef __attribute__((ext_vector_type(4))) float  floatx4;

__device__ __forceinline__ float sigm(float x)   { return 1.f / (1.f + __expf(-x)); }
__device__ __forceinline__ float tanh_f(float x) { return 1.f - 2.f / (1.f + __expf(2.f * x)); }

// fp32 -> bf16 hi (RNE-ish) + bf16 lo of the residual. |err| ~ 2^-16 rel.
__device__ __forceinline__ void bsplit(float a, unsigned short& h, unsigned short& l) {
    const unsigned int u  = __float_as_uint(a);
    const unsigned int hi = (u + 0x8000u) >> 16;
    const float fh = __uint_as_float(hi << 16);
    h = (unsigned short)hi;
    l = (unsigned short)(__float_as_uint(a - fh) >> 16);
}

// ---------------------------------------------------------------- prep ------
struct PrepArgs {
    const float* t_src[4];   // eWhh0, eWih1, eWhh1, dWhh0 -> [128,512]
    float*       t_dst[4];
    const float* d1x;  const float* d1h;  float* pack;   // dec L1 8-wide pack
    const float* wx1;  unsigned short* wh; unsigned short* wl;  // eWih1 bf16 split
};

__global__ void kPrep(PrepArgs a) {
    const int m = blockIdx.x;
    if (m < 4) {
        for (int i = threadIdx.x; i < G_ * H_; i += blockDim.x) {
            const int j = i >> 7, k = i & 127;
            a.t_dst[m][k * G_ + j] = a.t_src[m][i];
        }
    } else if (m == 4) {
        // pack[(k*128 + j4)*8 + g]   = dWih1[j4+128g][k]  (g=0..3)
        // pack[(k*128 + j4)*8 + 4+g] = dWhh1[j4+128g][k]
        for (int i = threadIdx.x; i < H_ * H_; i += blockDim.x) {
            const int k = i >> 7, j4 = i & 127;
            float* p = a.pack + ((size_t)k * H_ + j4) * 8;
#pragma unroll
            for (int g = 0; g < 4; g++) {
                p[g]     = a.d1x[(j4 + 128 * g) * H_ + k];
                p[4 + g] = a.d1h[(j4 + 128 * g) * H_ + k];
            }
        }
    } else {
        // eWih1 is [512][128] row-major = [n][k]: fragment-native, no transpose.
        for (int i = threadIdx.x; i < G_ * H_; i += blockDim.x) {
            unsigned short h, l;
            bsplit(a.wx1[i], h, l);
            a.wh[i] = h; a.wl[i] = l;
        }
    }
}

// --------------------------------- enc L0 (quad-gate, 4-way k, 512 thr) -----
__global__ __launch_bounds__(512, 2) void kA(
    const float* __restrict__ feat,   // [B,T]
    const float* __restrict__ whhT,   // [128,512] enc_Whh0^T
    const float* __restrict__ wih0,   // [512]
    const float* __restrict__ bias,   // [512]
    unsigned short* __restrict__ Ah,  // [CL][1024][128] bf16-hi of h
    unsigned short* __restrict__ Al,  // [CL][1024][128] bf16-lo
    float* __restrict__ hS, float* __restrict__ cS,
    int t0, int CL)
{
    __shared__ __align__(16) float h_sh[H_ * 4];     // [hid][bb]
    __shared__ __align__(16) float zp[4 * 2048];     // [kq][batch][gate]
    __shared__ __align__(16) float f_sh[84 * 4];

    const int tid = threadIdx.x;
    const int hid = tid & 127;        // = j4 (gate group) = act hid
    const int bb  = tid >> 7;         // = kq (k-quarter)  = act batch
    const int B0  = blockIdx.x * 4;

    float w[4][32];
#pragma unroll
    for (int g = 0; g < 4; g++)
#pragma unroll
        for (int k = 0; k < 32; k++)
            w[g][k] = whhT[(bb * 32 + k) * G_ + hid + 128 * g];

    const float bi = bias[hid],           bf = bias[hid + 128];
    const float bg = bias[hid + 256],     bo = bias[hid + 384];
    const float wxi = wih0[hid],          wxf = wih0[hid + 128];
    const float wxg = wih0[hid + 256],    wxo = wih0[hid + 384];

    for (int i = tid; i < CL * 4; i += 512)
        f_sh[i] = feat[(B0 + (i & 3)) * T_ + t0 + (i >> 2)];

    float c = 0.f;
    {
        float hv = 0.f;
        if (t0 != 0) { c = cS[(B0 + bb) * H_ + hid]; hv = hS[(B0 + bb) * H_ + hid]; }
        h_sh[hid * 4 + bb] = hv;
    }
    __syncthreads();

    const float* hb = h_sh + bb * 128;   // k-range bb*32..+31, [k][batch]
    for (int dt = 0; dt < CL; dt++) {
        float a[4][4] = {};
#pragma unroll
        for (int k = 0; k < 32; k++) {
            const float4 h4 = *(const float4*)&hb[k * 4];   // uniform broadcast
#pragma unroll
            for (int g = 0; g < 4; g++) {
                a[g][0] = __fmaf_rn(h4.x, w[g][k], a[g][0]);
                a[g][1] = __fmaf_rn(h4.y, w[g][k], a[g][1]);
                a[g][2] = __fmaf_rn(h4.z, w[g][k], a[g][2]);
                a[g][3] = __fmaf_rn(h4.w, w[g][k], a[g][3]);
            }
        }
#pragma unroll
        for (int g = 0; g < 4; g++)
#pragma unroll
            for (int b = 0; b < 4; b++)
                zp[bb * 2048 + b * 512 + hid + 128 * g] = a[g][b];
        __syncthreads();

        {
            const float x = f_sh[dt * 4 + bb];
            const int base = bb * 512 + hid;
            float zi = __fmaf_rn(wxi, x, bi);
            float zf = __fmaf_rn(wxf, x, bf);
            float zg = __fmaf_rn(wxg, x, bg);
            float zo = __fmaf_rn(wxo, x, bo);
#pragma unroll
            for (int q = 0; q < 4; q++) {
                zi += zp[q * 2048 + base];
                zf += zp[q * 2048 + base + 128];
                zg += zp[q * 2048 + base + 256];
                zo += zp[q * 2048 + base + 384];
            }
            c = sigm(zf) * c + sigm(zi) * tanh_f(zg);
            const float hv = sigm(zo) * tanh_f(c);
            h_sh[hid * 4 + bb] = hv;
            // bf16 split store, [dt][m][k] layout: fragment-native for kXm.
            unsigned short sh, sl;
            bsplit(hv, sh, sl);
            const size_t ai = ((size_t)dt * B_ + B0 + bb) * H_ + hid;
            Ah[ai] = sh; Al[ai] = sl;
        }
        __syncthreads();
    }
    hS[(B0 + bb) * H_ + hid] = h_sh[hid * 4 + bb];
    cS[(B0 + bb) * H_ + hid] = c;
}

// ----------------------- X1 GEMM via MFMA bf16 split-2 ----------------------
// C[dt][m=1024][n=512] = A[m][k=128] * W[n][k] + bias, 3-product bf16 split.
// Block: 128m x 128n, 4 waves (wave w owns rows w*32..+31).
// A-frag: lane%16 = m, k = 8*(lane/16)+j (contiguous -> 16B global load).
// B-frag: lane%16 = n, same k mapping, from XOR-swizzled LDS rows.
// D: row = (lane>>4)*4 + reg (A-spatial), col = lane&15 (B-spatial).
__global__ __launch_bounds__(256, 2) void kXm(
    const unsigned short* __restrict__ Ah,  // [CL][1024][128]
    const unsigned short* __restrict__ Al,
    const unsigned short* __restrict__ Wh,  // [512][128]
    const unsigned short* __restrict__ Wl,
    const float* __restrict__ bias,         // [512]
    float* __restrict__ X1)                 // [CL][1024][512]
{
    __shared__ __align__(16) unsigned short Bh[128 * 128];  // 32KB, rows 256B
    __shared__ __align__(16) unsigned short Bl[128 * 128];  // 32KB

    const int tid = threadIdx.x;
    const int n0  = blockIdx.y * 128;

    // Stage B slice. XOR swizzle (G4): byte ^= (row&7)<<4 within each row.
    for (int c = tid; c < 2048; c += 256) {
        const int n  = c >> 4;
        const int kb = (c & 15) << 4;
        const int sb = n * 256 + (kb ^ ((n & 7) << 4));
        *(float4*)((char*)Bh + sb) =
            *(const float4*)((const char*)Wh + (size_t)(n0 + n) * 256 + kb);
        *(float4*)((char*)Bl + sb) =
            *(const float4*)((const char*)Wl + (size_t)(n0 + n) * 256 + kb);
    }
    __syncthreads();

    const int lane = tid & 63;
    const int w    = tid >> 6;
    const int l15  = lane & 15;
    const int lq   = lane >> 4;
    const int dt   = blockIdx.z;
    const int m0   = blockIdx.x * 128 + w * 32;

    const size_t arow = ((size_t)dt * B_ + m0 + l15) * H_;
    const unsigned short* a0h = Ah + arow;
    const unsigned short* a0l = Al + arow;

    floatx4 acc[2][8];
#pragma unroll
    for (int i = 0; i < 2; i++)
#pragma unroll
        for (int j = 0; j < 8; j++)
            acc[i][j] = (floatx4){0.f, 0.f, 0.f, 0.f};

#pragma unroll
    for (int ks = 0; ks < 4; ks++) {
        const int kk = ks * 32 + 8 * lq;                 // element k base
        const short8 ah0 = *(const short8*)(a0h + kk);             // m-tile 0 hi
        const short8 al0 = *(const short8*)(a0l + kk);             // m-tile 0 lo
        const short8 ah1 = *(const short8*)(a0h + 16 * H_ + kk);   // m-tile 1 hi
        const short8 al1 = *(const short8*)(a0l + 16 * H_ + kk);   // m-tile 1 lo
        const int kbb = kk * 2;                          // byte k base
#pragma unroll
        for (int nt = 0; nt < 8; nt++) {
            const int row = nt * 16 + l15;
            const int sb  = row * 256 + (kbb ^ ((row & 7) << 4));
            const short8 bh = *(const short8*)((const char*)Bh + sb);
            const short8 bl = *(const short8*)((const char*)Bl + sb);
            acc[0][nt] = __builtin_amdgcn_mfma_f32_16x16x32_bf16(ah0, bh, acc[0][nt], 0, 0, 0);
            acc[1][nt] = __builtin_amdgcn_mfma_f32_16x16x32_bf16(ah1, bh, acc[1][nt], 0, 0, 0);
            acc[0][nt] = __builtin_amdgcn_mfma_f32_16x16x32_bf16(ah0, bl, acc[0][nt], 0, 0, 0);
            acc[1][nt] = __builtin_amdgcn_mfma_f32_16x16x32_bf16(ah1, bl, acc[1][nt], 0, 0, 0);
            acc[0][nt] = __builtin_amdgcn_mfma_f32_16x16x32_bf16(al0, bh, acc[0][nt], 0, 0, 0);
            acc[1][nt] = __builtin_amdgcn_mfma_f32_16x16x32_bf16(al1, bh, acc[1][nt], 0, 0, 0);
        }
    }

#pragma unroll
    for (int nt = 0; nt < 8; nt++) {
        const float bv = bias[n0 + nt * 16 + l15];
#pragma unroll
        for (int mt = 0; mt < 2; mt++) {
            const size_t orow =
                ((size_t)dt * B_ + m0 + mt * 16 + lq * 4) * G_ + n0 + nt * 16 + l15;
#pragma unroll
            for (int r = 0; r < 4; r++)
                X1[orow + (size_t)r * G_] = acc[mt][nt][r] + bv;
        }
    }
}

// --------------------------------- enc L1 (quad-gate, 4-way k, 512 thr) -----
__global__ __launch_bounds__(512, 2) void kB2(
    const float* __restrict__ X1,     // [CL][B][512] x-projection (+bias)
    const float* __restrict__ whhT,   // [128,512] enc_Whh1^T
    float* __restrict__ hS, float* __restrict__ cS,
    int t0, int CL)
{
    __shared__ __align__(16) float h_sh[H_ * 4];
    __shared__ __align__(16) float zp[4 * 2048];

    const int tid = threadIdx.x;
    const int hid = tid & 127;
    const int bb  = tid >> 7;
    const int B0  = blockIdx.x * 4;

    float w[4][32];
#pragma unroll
    for (int g = 0; g < 4; g++)
#pragma unroll
        for (int k = 0; k < 32; k++)
            w[g][k] = whhT[(bb * 32 + k) * G_ + hid + 128 * g];

    float c = 0.f;
    {
        float hv = 0.f;
        if (t0 != 0) { c = cS[(B0 + bb) * H_ + hid]; hv = hS[(B0 + bb) * H_ + hid]; }
        h_sh[hid * 4 + bb] = hv;
    }
    __syncthreads();

    const float* hb = h_sh + bb * 128;
    for (int dt = 0; dt < CL; dt++) {
        const size_t xb = ((size_t)dt * B_ + B0 + bb) * G_ + hid;
        const float xg0 = X1[xb];
        const float xg1 = X1[xb + 128];
        const float xg2 = X1[xb + 256];
        const float xg3 = X1[xb + 384];

        float a[4][4] = {};
#pragma unroll
        for (int k = 0; k < 32; k++) {
            const float4 h4 = *(const float4*)&hb[k * 4];
#pragma unroll
            for (int g = 0; g < 4; g++) {
                a[g][0] = __fmaf_rn(h4.x, w[g][k], a[g][0]);
                a[g][1] = __fmaf_rn(h4.y, w[g][k], a[g][1]);
                a[g][2] = __fmaf_rn(h4.z, w[g][k], a[g][2]);
                a[g][3] = __fmaf_rn(h4.w, w[g][k], a[g][3]);
            }
        }
#pragma unroll
        for (int g = 0; g < 4; g++)
#pragma unroll
            for (int b = 0; b < 4; b++)
                zp[bb * 2048 + b * 512 + hid + 128 * g] = a[g][b];
        __syncthreads();

        {
            const int base = bb * 512 + hid;
            float zi = xg0, zf = xg1, zg = xg2, zo = xg3;
#pragma unroll
            for (int q = 0; q < 4; q++) {
                zi += zp[q * 2048 + base];
                zf += zp[q * 2048 + base + 128];
                zg += zp[q * 2048 + base + 256];
                zo += zp[q * 2048 + base + 384];
            }
            c = sigm(zf) * c + sigm(zi) * tanh_f(zg);
            h_sh[hid * 4 + bb] = sigm(zo) * tanh_f(c);
        }
        __syncthreads();
    }
    hS[(B0 + bb) * H_ + hid] = h_sh[hid * 4 + bb];
    cS[(B0 + bb) * H_ + hid] = c;
}

// ------------------------------------------- decoder (quad-gate both dots) --
__global__ __launch_bounds__(512, 2) void kD(
    const float* __restrict__ h1S, const float* __restrict__ c1S,
    const float* __restrict__ h2S, const float* __restrict__ c2S,
    const float* __restrict__ whh0T,  // [128][512] dec_Whh0^T (register-resident)
    const float* __restrict__ wih0,   // [512]
    const float* __restrict__ b0,
    const float* __restrict__ packD1, // [128][128][8]
    const float* __restrict__ b1,
    const float* __restrict__ wo1,    // [128][128] W_out1 [hid][k] -> LDS rows
    const float* __restrict__ bo1,
    const float* __restrict__ wo2,
    const float* __restrict__ bo2,
    float* __restrict__ out)          // [B,TGT]
{
    __shared__ __align__(16) float h1_sh[H_ * 4];
    __shared__ __align__(16) float h2_sh[H_ * 4];
    __shared__ __align__(16) float h2t[4][H_];       // [bb][hid]
    __shared__ __align__(16) float zp[4 * 2048];
    __shared__ __align__(16) float wo1s[H_ * 132];   // rows [hid][k], pad 132
    __shared__ float rp[8];

    const int tid = threadIdx.x;
    const int hid = tid & 127;        // gate group / act hid
    const int bb  = tid >> 7;         // k-quarter / act batch
    const int B0  = blockIdx.x * 4;

    float w0[4][32];
#pragma unroll
    for (int g = 0; g < 4; g++)
#pragma unroll
        for (int k = 0; k < 32; k++)
            w0[g][k] = whh0T[(bb * 32 + k) * G_ + hid + 128 * g];

    const float b0i = b0[hid],        b0f = b0[hid + 128];
    const float b0g = b0[hid + 256],  b0o = b0[hid + 384];
    const float wxi = wih0[hid],      wxf = wih0[hid + 128];
    const float wxg = wih0[hid + 256], wxo = wih0[hid + 384];
    const float b1i = b1[hid],        b1f = b1[hid + 128];
    const float b1g = b1[hid + 256],  b1o = b1[hid + 384];

    for (int t = tid; t < H_ * 32; t += 512) {
        const int r = t >> 5, q = t & 31;
        *(float4*)&wo1s[r * 132 + q * 4] = *(const float4*)&wo1[r * H_ + q * 4];
    }

    const float wo2v = wo2[hid];
    const float bo1j = bo1[hid];
    const float bo2v = bo2[0];

    float c1 = c1S[(B0 + bb) * H_ + hid];
    float c2 = c2S[(B0 + bb) * H_ + hid];
    h1_sh[hid * 4 + bb] = h1S[(B0 + bb) * H_ + hid];
    {
        const float h2v = h2S[(B0 + bb) * H_ + hid];
        h2_sh[hid * 4 + bb] = h2v;
        h2t[bb][hid] = h2v;
    }
    if (tid < 8) rp[tid] = -0.5f * bo2v;   // so pred(step 0) = 0
    __syncthreads();

    const float* hb1 = h1_sh + bb * 128;
    const float* hb2 = h2_sh + bb * 128;
    const float* pk  = packD1 + ((size_t)bb * 32 * H_ + hid) * 8;

    for (int s = 0; s < TGT_; s++) {
        // ===== phase 1: L0 h-dot (reg weights) + head of h2(s-1), overlapped =====
        {
            float a[4][4] = {};
#pragma unroll
            for (int k = 0; k < 32; k++) {
                const float4 h4 = *(const float4*)&hb1[k * 4];
#pragma unroll
                for (int g = 0; g < 4; g++) {
                    a[g][0] = __fmaf_rn(h4.x, w0[g][k], a[g][0]);
                    a[g][1] = __fmaf_rn(h4.y, w0[g][k], a[g][1]);
                    a[g][2] = __fmaf_rn(h4.z, w0[g][k], a[g][2]);
                    a[g][3] = __fmaf_rn(h4.w, w0[g][k], a[g][3]);
                }
            }
#pragma unroll
            for (int g = 0; g < 4; g++)
#pragma unroll
                for (int b = 0; b < 4; b++)
                    zp[bb * 2048 + b * 512 + hid + 128 * g] = a[g][b];
        }
        {
            float hacc = bo1j;
#pragma unroll
            for (int q = 0; q < 32; q++) {
                const float4 hq = *(const float4*)&h2t[bb][q * 4];          // uniform
                const float4 wq = *(const float4*)&wo1s[hid * 132 + q * 4]; // lane-spread
                hacc = __fmaf_rn(hq.x, wq.x, hacc);
                hacc = __fmaf_rn(hq.y, wq.y, hacc);
                hacc = __fmaf_rn(hq.z, wq.z, hacc);
                hacc = __fmaf_rn(hq.w, wq.w, hacc);
            }
            float p = fmaxf(hacc, 0.f) * wo2v;
            p += __shfl_down(p, 32); p += __shfl_down(p, 16); p += __shfl_down(p, 8);
            p += __shfl_down(p, 4);  p += __shfl_down(p, 2);  p += __shfl_down(p, 1);
            if ((tid & 63) == 0) rp[tid >> 6] = p;
        }
        __syncthreads();

        // ===== phase 2: L0 act (+ x-term via pred), out write =====
        {
            const float pred = rp[2 * bb] + rp[2 * bb + 1] + bo2v;
            if (hid == 0 && s > 0) out[(B0 + bb) * TGT_ + (s - 1)] = pred;
            const int base = bb * 512 + hid;
            float zi = __fmaf_rn(wxi, pred, b0i);
            float zf = __fmaf_rn(wxf, pred, b0f);
            float zg = __fmaf_rn(wxg, pred, b0g);
            float zo = __fmaf_rn(wxo, pred, b0o);
#pragma unroll
            for (int q = 0; q < 4; q++) {
                zi += zp[q * 2048 + base];
                zf += zp[q * 2048 + base + 128];
                zg += zp[q * 2048 + base + 256];
                zo += zp[q * 2048 + base + 384];
            }
            c1 = sigm(zf) * c1 + sigm(zi) * tanh_f(zg);
            h1_sh[hid * 4 + bb] = sigm(zo) * tanh_f(c1);
        }
        __syncthreads();

        // ===== phase 3: L1 dot (L2 stream: 32 contiguous B per thread per k) =====
        {
            float d[4][4] = {};
#pragma unroll 8
            for (int k = 0; k < 32; k++) {
                const float4 wi = *(const float4*)&pk[(size_t)k * 1024];
                const float4 wh = *(const float4*)&pk[(size_t)k * 1024 + 4];
                const float4 p1 = *(const float4*)&hb1[k * 4];
                const float4 p2 = *(const float4*)&hb2[k * 4];
                d[0][0] = __fmaf_rn(p1.x, wi.x, __fmaf_rn(p2.x, wh.x, d[0][0]));
                d[0][1] = __fmaf_rn(p1.y, wi.x, __fmaf_rn(p2.y, wh.x, d[0][1]));
                d[0][2] = __fmaf_rn(p1.z, wi.x, __fmaf_rn(p2.z, wh.x, d[0][2]));
                d[0][3] = __fmaf_rn(p1.w, wi.x, __fmaf_rn(p2.w, wh.x, d[0][3]));
                d[1][0] = __fmaf_rn(p1.x, wi.y, __fmaf_rn(p2.x, wh.y, d[1][0]));
                d[1][1] = __fmaf_rn(p1.y, wi.y, __fmaf_rn(p2.y, wh.y, d[1][1]));
                d[1][2] = __fmaf_rn(p1.z, wi.y, __fmaf_rn(p2.z, wh.y, d[1][2]));
                d[1][3] = __fmaf_rn(p1.w, wi.y, __fmaf_rn(p2.w, wh.y, d[1][3]));
                d[2][0] = __fmaf_rn(p1.x, wi.z, __fmaf_rn(p2.x, wh.z, d[2][0]));
                d[2][1] = __fmaf_rn(p1.y, wi.z, __fmaf_rn(p2.y, wh.z, d[2][1]));
                d[2][2] = __fmaf_rn(p1.z, wi.z, __fmaf_rn(p2.z, wh.z, d[2][2]));
                d[2][3] = __fmaf_rn(p1.w, wi.z, __fmaf_rn(p2.w, wh.z, d[2][3]));
                d[3][0] = __fmaf_rn(p1.x, wi.w, __fmaf_rn(p2.x, wh.w, d[3][0]));
                d[3][1] = __fmaf_rn(p1.y, wi.w, __fmaf_rn(p2.y, wh.w, d[3][1]));
                d[3][2] = __fmaf_rn(p1.z, wi.w, __fmaf_rn(p2.z, wh.w, d[3][2]));
                d[3][3] = __fmaf_rn(p1.w, wi.w, __fmaf_rn(p2.w, wh.w, d[3][3]));
            }
#pragma unroll
            for (int g = 0; g < 4; g++)
#pragma unroll
                for (int b = 0; b < 4; b++)
                    zp[bb * 2048 + b * 512 + hid + 128 * g] = d[g][b];
        }
        __syncthreads();

        // ===== phase 4: L1 act =====
        {
            const int base = bb * 512 + hid;
            float zi = b1i, zf = b1f, zg = b1g, zo = b1o;
#pragma unroll
            for (int q = 0; q < 4; q++) {
                zi += zp[q * 2048 + base];
                zf += zp[q * 2048 + base + 128];
                zg += zp[q * 2048 + base + 256];
                zo += zp[q * 2048 + base + 384];
            }
            c2 = sigm(zf) * c2 + sigm(zi) * tanh_f(zg);
            const float h2v = sigm(zo) * tanh_f(c2);
            h2_sh[hid * 4 + bb] = h2v;
            h2t[bb][hid] = h2v;
        }
        __syncthreads();
    }

    // ===== epilogue: head of final h2 -> out[..][95] =====
    {
        float hacc = bo1j;
#pragma unroll
        for (int q = 0; q < 32; q++) {
            const float4 hq = *(const float4*)&h2t[bb][q * 4];
            const float4 wq = *(const float4*)&wo1s[hid * 132 + q * 4];
            hacc = __fmaf_rn(hq.x, wq.x, hacc);
            hacc = __fmaf_rn(hq.y, wq.y, hacc);
            hacc = __fmaf_rn(hq.z, wq.z, hacc);
            hacc = __fmaf_rn(hq.w, wq.w, hacc);
        }
        float p = fmaxf(hacc, 0.f) * wo2v;
        p += __shfl_down(p, 32); p += __shfl_down(p, 16); p += __shfl_down(p, 8);
        p += __shfl_down(p, 4);  p += __shfl_down(p, 2);  p += __shfl_down(p, 1);
        if ((tid & 63) == 0) rp[tid >> 6] = p;
    }
    __syncthreads();
    if (tid < 4)
        out[(B0 + tid) * TGT_ + (TGT_ - 1)] = rp[2 * tid] + rp[2 * tid + 1] + bo2v;
}

// ---------------------------------------------------------------- launch ----
extern "C" void kernel_launch(void* const* d_in, const int* in_sizes, int n_in,
                              void* d_out, int out_size, void* d_ws, size_t ws_size,
                              hipStream_t stream) {
    const float* feat  = (const float*)d_in[0];
    const float* eWih0 = (const float*)d_in[1];
    const float* eWhh0 = (const float*)d_in[2];
    const float* eB0   = (const float*)d_in[3];
    const float* eWih1 = (const float*)d_in[4];
    const float* eWhh1 = (const float*)d_in[5];
    const float* eB1   = (const float*)d_in[6];
    const float* dWih0 = (const float*)d_in[7];
    const float* dWhh0 = (const float*)d_in[8];
    const float* dB0   = (const float*)d_in[9];
    const float* dWih1 = (const float*)d_in[10];
    const float* dWhh1 = (const float*)d_in[11];
    const float* dB1   = (const float*)d_in[12];
    const float* Wo1   = (const float*)d_in[13];
    const float* bo1   = (const float*)d_in[14];
    const float* Wo2   = (const float*)d_in[15];
    const float* bo2   = (const float*)d_in[16];

    const size_t SZ_BH = (size_t)B_ * H_;     // 131072
    const size_t SZ_W  = (size_t)G_ * H_;     // 65536
    // + SZ_W floats for the eWih1 bf16 hi/lo pair (SZ_W ushorts each)
    const size_t fixed_f = 4 * SZ_BH + 4 * SZ_W + 2 * SZ_W + SZ_W + 64;

    // CL <= 42 so X1 + A-halves stay L3-resident
    static const int cands[] = {42, 32, 28, 24, 21, 16, 14, 12, 8, 7, 6, 4, 3, 2, 1};
    int CL = 1;
    for (int ci = 0; ci < 15; ci++) {
        const size_t need = (fixed_f + (size_t)cands[ci] * B_ * (H_ + G_)) * 4;
        if (need <= ws_size) { CL = cands[ci]; break; }
    }
    const int NC = T_ / CL;

    float* ws = (float*)d_ws;
    unsigned short* Ah = (unsigned short*)ws;            // [CL][1024][128] bf16-hi
    unsigned short* Al = Ah + (size_t)CL * B_ * H_;      // [CL][1024][128] bf16-lo
    float* X1    = ws + (size_t)CL * B_ * H_;            // [CL][1024][512] (Ah+Al = CL*B*H floats)
    float* h1S   = X1 + (size_t)CL * B_ * G_;
    float* c1S   = h1S + SZ_BH;
    float* h2S   = c1S + SZ_BH;
    float* c2S   = h2S + SZ_BH;
    float* wtE0  = c2S + SZ_BH;
    float* wtE1x = wtE0 + SZ_W;
    float* wtE1h = wtE1x + SZ_W;
    float* wtD0  = wtE1h + SZ_W;
    float* wtD1p = wtD0 + SZ_W;            // [128][128][8] = 2*SZ_W
    unsigned short* Wh = (unsigned short*)(wtD1p + 2 * SZ_W);  // [512][128] bf16-hi
    unsigned short* Wl = Wh + SZ_W;                            // [512][128] bf16-lo

    PrepArgs pa;
    pa.t_src[0] = eWhh0; pa.t_dst[0] = wtE0;
    pa.t_src[1] = eWih1; pa.t_dst[1] = wtE1x;
    pa.t_src[2] = eWhh1; pa.t_dst[2] = wtE1h;
    pa.t_src[3] = dWhh0; pa.t_dst[3] = wtD0;
    pa.d1x = dWih1; pa.d1h = dWhh1; pa.pack = wtD1p;
    pa.wx1 = eWih1; pa.wh = Wh; pa.wl = Wl;
    kPrep<<<6, 256, 0, stream>>>(pa);

    for (int c = 0; c < NC; c++) {
        const int t0 = c * CL;
        kA<<<NBLK_, 512, 0, stream>>>(feat, wtE0, eWih0, eB0, Ah, Al, h1S, c1S, t0, CL);
        kXm<<<dim3(8, 4, CL), 256, 0, stream>>>(Ah, Al, Wh, Wl, eB1, X1);
        kB2<<<NBLK_, 512, 0, stream>>>(X1, wtE1h, h2S, c2S, t0, CL);
    }
    kD<<<NBLK_, 512, 0, stream>>>(h1S, c1S, h2S, c2S,
                                  wtD0, dWih0, dB0,
                                  wtD1p, dB1,
                                  Wo1, bo1, Wo2, bo2,
                                  (float*)d_out);
}

// Round 2
// 4664.104 us; speedup vs baseline: 1.1776x; 1.1776x over previous
//
#include <hip/hip_runtime.h>

// Seq2SeqLSTMForecaster on MI355X — round 12.
// R11 post-mortem: kXm (MFMA GEMM) was neutral; the dominant cost is the two
// fp32-VALU recurrent kernels kA+kB2 (~3.2ms, VALU floor, MfmaUtil=0).
// This round: kA/kB2 -> MFMA bf16 split-2 recurrent kernels (kA2/kB3).
//  Key insight (D-layout verified by kXm passing): wave w takes n-tiles
//  {w, w+8, w+16, w+24} -> all 4 gates of cell (batch=4*(lane>>4)+reg,
//  hid=16w+(lane&15)) are lane-local; c-state stays in VGPRs; h goes through
//  LDS (bf16 hi/lo) once per step with ONE barrier; weights are register-
//  resident B-fragments (128 VGPR). Global Ah/Al stores deferred one step so
//  the pre-barrier vmcnt(0) drain is amortized.
//  kXm, kD: byte-identical to round 11.

#define B_    1024
#define T_    672
#define H_    128
#define G_    512      // 4*H
#define TGT_  96
#define NBLK_ 256

typedef __attribute__((ext_vector_type(8))) short  short8;
typedef __attribute__((ext_vector_type(4))) float  floatx4;

__device__ __forceinline__ float sigm(float x)   { return 1.f / (1.f + __expf(-x)); }
__device__ __forceinline__ float tanh_f(float x) { return 1.f - 2.f / (1.f + __expf(2.f * x)); }

// fp32 -> bf16 hi (RNE-ish) + bf16 lo of the residual. |err| ~ 2^-31 rel on
// the reconstructed product sum (split-2, 3 MFMA products).
__device__ __forceinline__ void bsplit(float a, unsigned short& h, unsigned short& l) {
    const unsigned int u  = __float_as_uint(a);
    const unsigned int hi = (u + 0x8000u) >> 16;
    const float fh = __uint_as_float(hi << 16);
    h = (unsigned short)hi;
    l = (unsigned short)(__float_as_uint(a - fh) >> 16);
}

// ---------------------------------------------------------------- prep ------
struct PrepArgs {
    const float* dwhh0; float* wtD0;                  // kD transpose
    const float* d1x; const float* d1h; float* pack;  // kD dec L1 pack
    const float* bsrc[3];        // eWih1, eWhh0, eWhh1  (all [512][128] = [n][k])
    unsigned short* bh[3];
    unsigned short* bl[3];
};

__global__ void kPrep(PrepArgs a) {
    const int m = blockIdx.x;
    if (m == 0) {
        for (int i = threadIdx.x; i < G_ * H_; i += blockDim.x) {
            const int j = i >> 7, k = i & 127;
            a.wtD0[k * G_ + j] = a.dwhh0[i];
        }
    } else if (m == 1) {
        // pack[(k*128 + j4)*8 + g]   = dWih1[j4+128g][k]  (g=0..3)
        // pack[(k*128 + j4)*8 + 4+g] = dWhh1[j4+128g][k]
        for (int i = threadIdx.x; i < H_ * H_; i += blockDim.x) {
            const int k = i >> 7, j4 = i & 127;
            float* p = a.pack + ((size_t)k * H_ + j4) * 8;
#pragma unroll
            for (int g = 0; g < 4; g++) {
                p[g]     = a.d1x[(j4 + 128 * g) * H_ + k];
                p[4 + g] = a.d1h[(j4 + 128 * g) * H_ + k];
            }
        }
    } else {
        const int s = m - 2;
        const float* src = a.bsrc[s];
        unsigned short* dh = a.bh[s];
        unsigned short* dl = a.bl[s];
        for (int i = threadIdx.x; i < G_ * H_; i += blockDim.x) {
            unsigned short h, l;
            bsplit(src[i], h, l);
            dh[i] = h; dl[i] = l;
        }
    }
}

// ------------------- enc L0: MFMA recurrent, 16 batches/block ---------------
// Per step: z[16 batch][512 gate] = h[16][128] * Whh0^T via 16x16x32 bf16
// split-2 (3 products). Wave w owns n-tiles {w,w+8,w+16,w+24} -> lane-local
// gates. One barrier/step; c in VGPRs; h via LDS bf16 hi/lo double-buffer.
__global__ __launch_bounds__(512, 2) void kA2(
    const float* __restrict__ feat,          // [B, T]
    const unsigned short* __restrict__ WHh,  // eWhh0 bf16-hi [512][128]
    const unsigned short* __restrict__ WHl,  // lo
    const float* __restrict__ wih0,          // [512]
    const float* __restrict__ bias,          // [512]
    unsigned short* __restrict__ Ah,         // [CL][1024][128] bf16-hi of h
    unsigned short* __restrict__ Al,         // lo
    float* __restrict__ hS, float* __restrict__ cS,
    int t0, int CL)
{
    __shared__ __align__(16) unsigned short hh[2][16][136];
    __shared__ __align__(16) unsigned short hl[2][16][136];
    __shared__ __align__(16) float fsh[672];   // [dt][16]

    const int tid  = threadIdx.x;
    const int lane = tid & 63;
    const int w    = tid >> 6;       // wave 0..7
    const int c15  = lane & 15;
    const int q    = lane >> 4;      // 0..3
    const int BG   = blockIdx.x * 16;

    // B-fragments: wave w's gates n = 16w + 128g + c15; k = 32kt + 8q + j.
    short8 wh[4][4], wl[4][4];
#pragma unroll
    for (int g = 0; g < 4; g++)
#pragma unroll
        for (int kt = 0; kt < 4; kt++) {
            const size_t off = (size_t)(16 * w + 128 * g + c15) * H_ + 32 * kt + 8 * q;
            wh[g][kt] = *(const short8*)(WHh + off);
            wl[g][kt] = *(const short8*)(WHl + off);
        }

    float bz[4], wx[4];
#pragma unroll
    for (int g = 0; g < 4; g++) {
        bz[g] = bias[16 * w + 128 * g + c15];
        wx[g] = wih0[16 * w + 128 * g + c15];
    }

    for (int i = tid; i < CL * 16; i += 512)
        fsh[i] = feat[(BG + (i & 15)) * T_ + t0 + (i >> 4)];

    float cc[4], hv[4];
#pragma unroll
    for (int r = 0; r < 4; r++) { cc[r] = 0.f; hv[r] = 0.f; }
    if (t0 != 0) {
#pragma unroll
        for (int r = 0; r < 4; r++) {
            const size_t si = (size_t)(BG + 4 * q + r) * H_ + 16 * w + c15;
            cc[r] = cS[si]; hv[r] = hS[si];
        }
    }
#pragma unroll
    for (int r = 0; r < 4; r++) {
        unsigned short hi, lo; bsplit(hv[r], hi, lo);
        hh[0][4 * q + r][16 * w + c15] = hi;
        hl[0][4 * q + r][16 * w + c15] = lo;
    }
    __syncthreads();

    int pb = 0;
    unsigned int hp[4];    // packed h(dt-1): hi | lo<<16, for deferred store

    for (int dt = 0; dt < CL; dt++) {
        // deferred global store of h(dt-1): issued right after the barrier so
        // the next barrier's vmcnt(0) drain is fully hidden by this step.
        if (dt > 0) {
#pragma unroll
            for (int r = 0; r < 4; r++) {
                const size_t ai = ((size_t)(dt - 1) * B_ + BG + 4 * q + r) * H_ + 16 * w + c15;
                Ah[ai] = (unsigned short)(hp[r] & 0xffffu);
                Al[ai] = (unsigned short)(hp[r] >> 16);
            }
        }

        floatx4 acc[4];
#pragma unroll
        for (int g = 0; g < 4; g++) acc[g] = (floatx4){0.f, 0.f, 0.f, 0.f};

#pragma unroll
        for (int kt = 0; kt < 4; kt++) {
            const short8 ahv = *(const short8*)&hh[pb][c15][32 * kt + 8 * q];
            const short8 alv = *(const short8*)&hl[pb][c15][32 * kt + 8 * q];
#pragma unroll
            for (int g = 0; g < 4; g++) {
                acc[g] = __builtin_amdgcn_mfma_f32_16x16x32_bf16(ahv, wh[g][kt], acc[g], 0, 0, 0);
                acc[g] = __builtin_amdgcn_mfma_f32_16x16x32_bf16(ahv, wl[g][kt], acc[g], 0, 0, 0);
                acc[g] = __builtin_amdgcn_mfma_f32_16x16x32_bf16(alv, wh[g][kt], acc[g], 0, 0, 0);
            }
        }

        const int nb = pb ^ 1;
#pragma unroll
        for (int r = 0; r < 4; r++) {
            const float x = fsh[dt * 16 + 4 * q + r];
            const float zi = acc[0][r] + __fmaf_rn(wx[0], x, bz[0]);
            const float zf = acc[1][r] + __fmaf_rn(wx[1], x, bz[1]);
            const float zg = acc[2][r] + __fmaf_rn(wx[2], x, bz[2]);
            const float zo = acc[3][r] + __fmaf_rn(wx[3], x, bz[3]);
            cc[r] = sigm(zf) * cc[r] + sigm(zi) * tanh_f(zg);
            const float h = sigm(zo) * tanh_f(cc[r]);
            hv[r] = h;
            unsigned short hi, lo; bsplit(h, hi, lo);
            hp[r] = (unsigned int)hi | ((unsigned int)lo << 16);
            hh[nb][4 * q + r][16 * w + c15] = hi;
            hl[nb][4 * q + r][16 * w + c15] = lo;
        }
        __syncthreads();
        pb = nb;
    }

#pragma unroll
    for (int r = 0; r < 4; r++) {
        const size_t ai = ((size_t)(CL - 1) * B_ + BG + 4 * q + r) * H_ + 16 * w + c15;
        Ah[ai] = (unsigned short)(hp[r] & 0xffffu);
        Al[ai] = (unsigned short)(hp[r] >> 16);
        const size_t si = (size_t)(BG + 4 * q + r) * H_ + 16 * w + c15;
        hS[si] = hv[r]; cS[si] = cc[r];
    }
}

// ----------------------- X1 GEMM via MFMA bf16 split-2 ----------------------
__global__ __launch_bounds__(256, 2) void kXm(
    const unsigned short* __restrict__ Ah,  // [CL][1024][128]
    const unsigned short* __restrict__ Al,
    const unsigned short* __restrict__ Wh,  // [512][128]
    const unsigned short* __restrict__ Wl,
    const float* __restrict__ bias,         // [512]
    float* __restrict__ X1)                 // [CL][1024][512]
{
    __shared__ __align__(16) unsigned short Bh[128 * 128];
    __shared__ __align__(16) unsigned short Bl[128 * 128];

    const int tid = threadIdx.x;
    const int n0  = blockIdx.y * 128;

    for (int c = tid; c < 2048; c += 256) {
        const int n  = c >> 4;
        const int kb = (c & 15) << 4;
        const int sb = n * 256 + (kb ^ ((n & 7) << 4));
        *(float4*)((char*)Bh + sb) =
            *(const float4*)((const char*)Wh + (size_t)(n0 + n) * 256 + kb);
        *(float4*)((char*)Bl + sb) =
            *(const float4*)((const char*)Wl + (size_t)(n0 + n) * 256 + kb);
    }
    __syncthreads();

    const int lane = tid & 63;
    const int w    = tid >> 6;
    const int l15  = lane & 15;
    const int lq   = lane >> 4;
    const int dt   = blockIdx.z;
    const int m0   = blockIdx.x * 128 + w * 32;

    const size_t arow = ((size_t)dt * B_ + m0 + l15) * H_;
    const unsigned short* a0h = Ah + arow;
    const unsigned short* a0l = Al + arow;

    floatx4 acc[2][8];
#pragma unroll
    for (int i = 0; i < 2; i++)
#pragma unroll
        for (int j = 0; j < 8; j++)
            acc[i][j] = (floatx4){0.f, 0.f, 0.f, 0.f};

#pragma unroll
    for (int ks = 0; ks < 4; ks++) {
        const int kk = ks * 32 + 8 * lq;
        const short8 ah0 = *(const short8*)(a0h + kk);
        const short8 al0 = *(const short8*)(a0l + kk);
        const short8 ah1 = *(const short8*)(a0h + 16 * H_ + kk);
        const short8 al1 = *(const short8*)(a0l + 16 * H_ + kk);
        const int kbb = kk * 2;
#pragma unroll
        for (int nt = 0; nt < 8; nt++) {
            const int row = nt * 16 + l15;
            const int sb  = row * 256 + (kbb ^ ((row & 7) << 4));
            const short8 bh = *(const short8*)((const char*)Bh + sb);
            const short8 bl = *(const short8*)((const char*)Bl + sb);
            acc[0][nt] = __builtin_amdgcn_mfma_f32_16x16x32_bf16(ah0, bh, acc[0][nt], 0, 0, 0);
            acc[1][nt] = __builtin_amdgcn_mfma_f32_16x16x32_bf16(ah1, bh, acc[1][nt], 0, 0, 0);
            acc[0][nt] = __builtin_amdgcn_mfma_f32_16x16x32_bf16(ah0, bl, acc[0][nt], 0, 0, 0);
            acc[1][nt] = __builtin_amdgcn_mfma_f32_16x16x32_bf16(ah1, bl, acc[1][nt], 0, 0, 0);
            acc[0][nt] = __builtin_amdgcn_mfma_f32_16x16x32_bf16(al0, bh, acc[0][nt], 0, 0, 0);
            acc[1][nt] = __builtin_amdgcn_mfma_f32_16x16x32_bf16(al1, bh, acc[1][nt], 0, 0, 0);
        }
    }

#pragma unroll
    for (int nt = 0; nt < 8; nt++) {
        const float bv = bias[n0 + nt * 16 + l15];
#pragma unroll
        for (int mt = 0; mt < 2; mt++) {
            const size_t orow =
                ((size_t)dt * B_ + m0 + mt * 16 + lq * 4) * G_ + n0 + nt * 16 + l15;
#pragma unroll
            for (int r = 0; r < 4; r++)
                X1[orow + (size_t)r * G_] = acc[mt][nt][r] + bv;
        }
    }
}

// ------------------- enc L1: MFMA recurrent, 16 batches/block ---------------
// Same structure as kA2; x-term comes from X1 (bias already included), loaded
// lane-locally at step start and consumed in the act phase (latency hidden).
__global__ __launch_bounds__(512, 2) void kB3(
    const float* __restrict__ X1,            // [CL][B][512]
    const unsigned short* __restrict__ WHh,  // eWhh1 bf16-hi [512][128]
    const unsigned short* __restrict__ WHl,
    float* __restrict__ hS, float* __restrict__ cS,
    int t0, int CL)
{
    __shared__ __align__(16) unsigned short hh[2][16][136];
    __shared__ __align__(16) unsigned short hl[2][16][136];

    const int tid  = threadIdx.x;
    const int lane = tid & 63;
    const int w    = tid >> 6;
    const int c15  = lane & 15;
    const int q    = lane >> 4;
    const int BG   = blockIdx.x * 16;

    short8 wh[4][4], wl[4][4];
#pragma unroll
    for (int g = 0; g < 4; g++)
#pragma unroll
        for (int kt = 0; kt < 4; kt++) {
            const size_t off = (size_t)(16 * w + 128 * g + c15) * H_ + 32 * kt + 8 * q;
            wh[g][kt] = *(const short8*)(WHh + off);
            wl[g][kt] = *(const short8*)(WHl + off);
        }

    float cc[4], hv[4];
#pragma unroll
    for (int r = 0; r < 4; r++) { cc[r] = 0.f; hv[r] = 0.f; }
    if (t0 != 0) {
#pragma unroll
        for (int r = 0; r < 4; r++) {
            const size_t si = (size_t)(BG + 4 * q + r) * H_ + 16 * w + c15;
            cc[r] = cS[si]; hv[r] = hS[si];
        }
    }
#pragma unroll
    for (int r = 0; r < 4; r++) {
        unsigned short hi, lo; bsplit(hv[r], hi, lo);
        hh[0][4 * q + r][16 * w + c15] = hi;
        hl[0][4 * q + r][16 * w + c15] = lo;
    }
    __syncthreads();

    int pb = 0;

    for (int dt = 0; dt < CL; dt++) {
        // x-projection for this step's cells: issued early, used in act phase.
        float x1v[4][4];
#pragma unroll
        for (int g = 0; g < 4; g++)
#pragma unroll
            for (int r = 0; r < 4; r++)
                x1v[g][r] = X1[((size_t)dt * B_ + BG + 4 * q + r) * G_ + 16 * w + 128 * g + c15];

        floatx4 acc[4];
#pragma unroll
        for (int g = 0; g < 4; g++) acc[g] = (floatx4){0.f, 0.f, 0.f, 0.f};

#pragma unroll
        for (int kt = 0; kt < 4; kt++) {
            const short8 ahv = *(const short8*)&hh[pb][c15][32 * kt + 8 * q];
            const short8 alv = *(const short8*)&hl[pb][c15][32 * kt + 8 * q];
#pragma unroll
            for (int g = 0; g < 4; g++) {
                acc[g] = __builtin_amdgcn_mfma_f32_16x16x32_bf16(ahv, wh[g][kt], acc[g], 0, 0, 0);
                acc[g] = __builtin_amdgcn_mfma_f32_16x16x32_bf16(ahv, wl[g][kt], acc[g], 0, 0, 0);
                acc[g] = __builtin_amdgcn_mfma_f32_16x16x32_bf16(alv, wh[g][kt], acc[g], 0, 0, 0);
            }
        }

        const int nb = pb ^ 1;
#pragma unroll
        for (int r = 0; r < 4; r++) {
            const float zi = acc[0][r] + x1v[0][r];
            const float zf = acc[1][r] + x1v[1][r];
            const float zg = acc[2][r] + x1v[2][r];
            const float zo = acc[3][r] + x1v[3][r];
            cc[r] = sigm(zf) * cc[r] + sigm(zi) * tanh_f(zg);
            const float h = sigm(zo) * tanh_f(cc[r]);
            hv[r] = h;
            unsigned short hi, lo; bsplit(h, hi, lo);
            hh[nb][4 * q + r][16 * w + c15] = hi;
            hl[nb][4 * q + r][16 * w + c15] = lo;
        }
        __syncthreads();
        pb = nb;
    }

#pragma unroll
    for (int r = 0; r < 4; r++) {
        const size_t si = (size_t)(BG + 4 * q + r) * H_ + 16 * w + c15;
        hS[si] = hv[r]; cS[si] = cc[r];
    }
}

// ------------------------------------------- decoder (quad-gate both dots) --
__global__ __launch_bounds__(512, 2) void kD(
    const float* __restrict__ h1S, const float* __restrict__ c1S,
    const float* __restrict__ h2S, const float* __restrict__ c2S,
    const float* __restrict__ whh0T,  // [128][512] dec_Whh0^T (register-resident)
    const float* __restrict__ wih0,   // [512]
    const float* __restrict__ b0,
    const float* __restrict__ packD1, // [128][128][8]
    const float* __restrict__ b1,
    const float* __restrict__ wo1,    // [128][128] W_out1 [hid][k] -> LDS rows
    const float* __restrict__ bo1,
    const float* __restrict__ wo2,
    const float* __restrict__ bo2,
    float* __restrict__ out)          // [B,TGT]
{
    __shared__ __align__(16) float h1_sh[H_ * 4];
    __shared__ __align__(16) float h2_sh[H_ * 4];
    __shared__ __align__(16) float h2t[4][H_];       // [bb][hid]
    __shared__ __align__(16) float zp[4 * 2048];
    __shared__ __align__(16) float wo1s[H_ * 132];   // rows [hid][k], pad 132
    __shared__ float rp[8];

    const int tid = threadIdx.x;
    const int hid = tid & 127;        // gate group / act hid
    const int bb  = tid >> 7;         // k-quarter / act batch
    const int B0  = blockIdx.x * 4;

    float w0[4][32];
#pragma unroll
    for (int g = 0; g < 4; g++)
#pragma unroll
        for (int k = 0; k < 32; k++)
            w0[g][k] = whh0T[(bb * 32 + k) * G_ + hid + 128 * g];

    const float b0i = b0[hid],        b0f = b0[hid + 128];
    const float b0g = b0[hid + 256],  b0o = b0[hid + 384];
    const float wxi = wih0[hid],      wxf = wih0[hid + 128];
    const float wxg = wih0[hid + 256], wxo = wih0[hid + 384];
    const float b1i = b1[hid],        b1f = b1[hid + 128];
    const float b1g = b1[hid + 256],  b1o = b1[hid + 384];

    for (int t = tid; t < H_ * 32; t += 512) {
        const int r = t >> 5, q = t & 31;
        *(float4*)&wo1s[r * 132 + q * 4] = *(const float4*)&wo1[r * H_ + q * 4];
    }

    const float wo2v = wo2[hid];
    const float bo1j = bo1[hid];
    const float bo2v = bo2[0];

    float c1 = c1S[(B0 + bb) * H_ + hid];
    float c2 = c2S[(B0 + bb) * H_ + hid];
    h1_sh[hid * 4 + bb] = h1S[(B0 + bb) * H_ + hid];
    {
        const float h2v = h2S[(B0 + bb) * H_ + hid];
        h2_sh[hid * 4 + bb] = h2v;
        h2t[bb][hid] = h2v;
    }
    if (tid < 8) rp[tid] = -0.5f * bo2v;   // so pred(step 0) = 0
    __syncthreads();

    const float* hb1 = h1_sh + bb * 128;
    const float* hb2 = h2_sh + bb * 128;
    const float* pk  = packD1 + ((size_t)bb * 32 * H_ + hid) * 8;

    for (int s = 0; s < TGT_; s++) {
        // ===== phase 1: L0 h-dot (reg weights) + head of h2(s-1), overlapped =====
        {
            float a[4][4] = {};
#pragma unroll
            for (int k = 0; k < 32; k++) {
                const float4 h4 = *(const float4*)&hb1[k * 4];
#pragma unroll
                for (int g = 0; g < 4; g++) {
                    a[g][0] = __fmaf_rn(h4.x, w0[g][k], a[g][0]);
                    a[g][1] = __fmaf_rn(h4.y, w0[g][k], a[g][1]);
                    a[g][2] = __fmaf_rn(h4.z, w0[g][k], a[g][2]);
                    a[g][3] = __fmaf_rn(h4.w, w0[g][k], a[g][3]);
                }
            }
#pragma unroll
            for (int g = 0; g < 4; g++)
#pragma unroll
                for (int b = 0; b < 4; b++)
                    zp[bb * 2048 + b * 512 + hid + 128 * g] = a[g][b];
        }
        {
            float hacc = bo1j;
#pragma unroll
            for (int q = 0; q < 32; q++) {
                const float4 hq = *(const float4*)&h2t[bb][q * 4];          // uniform
                const float4 wq = *(const float4*)&wo1s[hid * 132 + q * 4]; // lane-spread
                hacc = __fmaf_rn(hq.x, wq.x, hacc);
                hacc = __fmaf_rn(hq.y, wq.y, hacc);
                hacc = __fmaf_rn(hq.z, wq.z, hacc);
                hacc = __fmaf_rn(hq.w, wq.w, hacc);
            }
            float p = fmaxf(hacc, 0.f) * wo2v;
            p += __shfl_down(p, 32); p += __shfl_down(p, 16); p += __shfl_down(p, 8);
            p += __shfl_down(p, 4);  p += __shfl_down(p, 2);  p += __shfl_down(p, 1);
            if ((tid & 63) == 0) rp[tid >> 6] = p;
        }
        __syncthreads();

        // ===== phase 2: L0 act (+ x-term via pred), out write =====
        {
            const float pred = rp[2 * bb] + rp[2 * bb + 1] + bo2v;
            if (hid == 0 && s > 0) out[(B0 + bb) * TGT_ + (s - 1)] = pred;
            const int base = bb * 512 + hid;
            float zi = __fmaf_rn(wxi, pred, b0i);
            float zf = __fmaf_rn(wxf, pred, b0f);
            float zg = __fmaf_rn(wxg, pred, b0g);
            float zo = __fmaf_rn(wxo, pred, b0o);
#pragma unroll
            for (int q = 0; q < 4; q++) {
                zi += zp[q * 2048 + base];
                zf += zp[q * 2048 + base + 128];
                zg += zp[q * 2048 + base + 256];
                zo += zp[q * 2048 + base + 384];
            }
            c1 = sigm(zf) * c1 + sigm(zi) * tanh_f(zg);
            h1_sh[hid * 4 + bb] = sigm(zo) * tanh_f(c1);
        }
        __syncthreads();

        // ===== phase 3: L1 dot (L2 stream: 32 contiguous B per thread per k) =====
        {
            float d[4][4] = {};
#pragma unroll 8
            for (int k = 0; k < 32; k++) {
                const float4 wi = *(const float4*)&pk[(size_t)k * 1024];
                const float4 wh = *(const float4*)&pk[(size_t)k * 1024 + 4];
                const float4 p1 = *(const float4*)&hb1[k * 4];
                const float4 p2 = *(const float4*)&hb2[k * 4];
                d[0][0] = __fmaf_rn(p1.x, wi.x, __fmaf_rn(p2.x, wh.x, d[0][0]));
                d[0][1] = __fmaf_rn(p1.y, wi.x, __fmaf_rn(p2.y, wh.x, d[0][1]));
                d[0][2] = __fmaf_rn(p1.z, wi.x, __fmaf_rn(p2.z, wh.x, d[0][2]));
                d[0][3] = __fmaf_rn(p1.w, wi.x, __fmaf_rn(p2.w, wh.x, d[0][3]));
                d[1][0] = __fmaf_rn(p1.x, wi.y, __fmaf_rn(p2.x, wh.y, d[1][0]));
                d[1][1] = __fmaf_rn(p1.y, wi.y, __fmaf_rn(p2.y, wh.y, d[1][1]));
                d[1][2] = __fmaf_rn(p1.z, wi.y, __fmaf_rn(p2.z, wh.y, d[1][2]));
                d[1][3] = __fmaf_rn(p1.w, wi.y, __fmaf_rn(p2.w, wh.y, d[1][3]));
                d[2][0] = __fmaf_rn(p1.x, wi.z, __fmaf_rn(p2.x, wh.z, d[2][0]));
                d[2][1] = __fmaf_rn(p1.y, wi.z, __fmaf_rn(p2.y, wh.z, d[2][1]));
                d[2][2] = __fmaf_rn(p1.z, wi.z, __fmaf_rn(p2.z, wh.z, d[2][2]));
                d[2][3] = __fmaf_rn(p1.w, wi.z, __fmaf_rn(p2.w, wh.z, d[2][3]));
                d[3][0] = __fmaf_rn(p1.x, wi.w, __fmaf_rn(p2.x, wh.w, d[3][0]));
                d[3][1] = __fmaf_rn(p1.y, wi.w, __fmaf_rn(p2.y, wh.w, d[3][1]));
                d[3][2] = __fmaf_rn(p1.z, wi.w, __fmaf_rn(p2.z, wh.w, d[3][2]));
                d[3][3] = __fmaf_rn(p1.w, wi.w, __fmaf_rn(p2.w, wh.w, d[3][3]));
            }
#pragma unroll
            for (int g = 0; g < 4; g++)
#pragma unroll
                for (int b = 0; b < 4; b++)
                    zp[bb * 2048 + b * 512 + hid + 128 * g] = d[g][b];
        }
        __syncthreads();

        // ===== phase 4: L1 act =====
        {
            const int base = bb * 512 + hid;
            float zi = b1i, zf = b1f, zg = b1g, zo = b1o;
#pragma unroll
            for (int q = 0; q < 4; q++) {
                zi += zp[q * 2048 + base];
                zf += zp[q * 2048 + base + 128];
                zg += zp[q * 2048 + base + 256];
                zo += zp[q * 2048 + base + 384];
            }
            c2 = sigm(zf) * c2 + sigm(zi) * tanh_f(zg);
            const float h2v = sigm(zo) * tanh_f(c2);
            h2_sh[hid * 4 + bb] = h2v;
            h2t[bb][hid] = h2v;
        }
        __syncthreads();
    }

    // ===== epilogue: head of final h2 -> out[..][95] =====
    {
        float hacc = bo1j;
#pragma unroll
        for (int q = 0; q < 32; q++) {
            const float4 hq = *(const float4*)&h2t[bb][q * 4];
            const float4 wq = *(const float4*)&wo1s[hid * 132 + q * 4];
            hacc = __fmaf_rn(hq.x, wq.x, hacc);
            hacc = __fmaf_rn(hq.y, wq.y, hacc);
            hacc = __fmaf_rn(hq.z, wq.z, hacc);
            hacc = __fmaf_rn(hq.w, wq.w, hacc);
        }
        float p = fmaxf(hacc, 0.f) * wo2v;
        p += __shfl_down(p, 32); p += __shfl_down(p, 16); p += __shfl_down(p, 8);
        p += __shfl_down(p, 4);  p += __shfl_down(p, 2);  p += __shfl_down(p, 1);
        if ((tid & 63) == 0) rp[tid >> 6] = p;
    }
    __syncthreads();
    if (tid < 4)
        out[(B0 + tid) * TGT_ + (TGT_ - 1)] = rp[2 * tid] + rp[2 * tid + 1] + bo2v;
}

// ---------------------------------------------------------------- launch ----
extern "C" void kernel_launch(void* const* d_in, const int* in_sizes, int n_in,
                              void* d_out, int out_size, void* d_ws, size_t ws_size,
                              hipStream_t stream) {
    const float* feat  = (const float*)d_in[0];
    const float* eWih0 = (const float*)d_in[1];
    const float* eWhh0 = (const float*)d_in[2];
    const float* eB0   = (const float*)d_in[3];
    const float* eWih1 = (const float*)d_in[4];
    const float* eWhh1 = (const float*)d_in[5];
    const float* eB1   = (const float*)d_in[6];
    const float* dWih0 = (const float*)d_in[7];
    const float* dWhh0 = (const float*)d_in[8];
    const float* dB0   = (const float*)d_in[9];
    const float* dWih1 = (const float*)d_in[10];
    const float* dWhh1 = (const float*)d_in[11];
    const float* dB1   = (const float*)d_in[12];
    const float* Wo1   = (const float*)d_in[13];
    const float* bo1   = (const float*)d_in[14];
    const float* Wo2   = (const float*)d_in[15];
    const float* bo2   = (const float*)d_in[16];

    const size_t SZ_BH = (size_t)B_ * H_;     // 131072
    const size_t SZ_W  = (size_t)G_ * H_;     // 65536
    // fixed: h/c states (4*BH) + wtD0 (W) + pack (2W) + 3 bf16 split pairs (3W)
    const size_t fixed_f = 4 * SZ_BH + 6 * SZ_W + 64;

    // CL <= 42 so X1 + A-halves stay L3-resident
    static const int cands[] = {42, 32, 28, 24, 21, 16, 14, 12, 8, 7, 6, 4, 3, 2, 1};
    int CL = 1;
    for (int ci = 0; ci < 15; ci++) {
        const size_t need = (fixed_f + (size_t)cands[ci] * B_ * (H_ + G_)) * 4;
        if (need <= ws_size) { CL = cands[ci]; break; }
    }
    const int NC = T_ / CL;

    float* ws = (float*)d_ws;
    unsigned short* Ah = (unsigned short*)ws;            // [CL][1024][128] bf16-hi
    unsigned short* Al = Ah + (size_t)CL * B_ * H_;      // [CL][1024][128] bf16-lo
    float* X1    = ws + (size_t)CL * B_ * H_;            // [CL][1024][512]
    float* h1S   = X1 + (size_t)CL * B_ * G_;
    float* c1S   = h1S + SZ_BH;
    float* h2S   = c1S + SZ_BH;
    float* c2S   = h2S + SZ_BH;
    float* wtD0  = c2S + SZ_BH;
    float* wtD1p = wtD0 + SZ_W;                          // [128][128][8] = 2*SZ_W
    unsigned short* Wh  = (unsigned short*)(wtD1p + 2 * SZ_W);  // eWih1 split
    unsigned short* Wl  = Wh + SZ_W;
    unsigned short* H0h = Wl + SZ_W;                            // eWhh0 split
    unsigned short* H0l = H0h + SZ_W;
    unsigned short* H1h = H0l + SZ_W;                           // eWhh1 split
    unsigned short* H1l = H1h + SZ_W;

    PrepArgs pa;
    pa.dwhh0 = dWhh0; pa.wtD0 = wtD0;
    pa.d1x = dWih1; pa.d1h = dWhh1; pa.pack = wtD1p;
    pa.bsrc[0] = eWih1; pa.bh[0] = Wh;  pa.bl[0] = Wl;
    pa.bsrc[1] = eWhh0; pa.bh[1] = H0h; pa.bl[1] = H0l;
    pa.bsrc[2] = eWhh1; pa.bh[2] = H1h; pa.bl[2] = H1l;
    kPrep<<<5, 256, 0, stream>>>(pa);

    for (int c = 0; c < NC; c++) {
        const int t0 = c * CL;
        kA2<<<64, 512, 0, stream>>>(feat, H0h, H0l, eWih0, eB0, Ah, Al, h1S, c1S, t0, CL);
        kXm<<<dim3(8, 4, CL), 256, 0, stream>>>(Ah, Al, Wh, Wl, eB1, X1);
        kB3<<<64, 512, 0, stream>>>(X1, H1h, H1l, h2S, c2S, t0, CL);
    }
    kD<<<NBLK_, 512, 0, stream>>>(h1S, c1S, h2S, c2S,
                                  wtD0, dWih0, dB0,
                                  wtD1p, dB1,
                                  Wo1, bo1, Wo2, bo2,
                                  (float*)d_out);
}